// Round 3
// baseline (130.814 us; speedup 1.0000x reference)
//
#include <hip/hip_runtime.h>
#include <stdint.h>
#include <math.h>

#pragma clang fp contract(off)

#define B_BATCH 4
#define K_HARM  64
#define T_TOT   144000   // ceil(3*48000/240)*240 == 3*48000
#define N_SAMP  144000
#define WF      128      // pole<=0.93937 -> pole^128 ~ 3e-4; *noise_env(<=0.011) -> <2e-6 abs

// ws layout (float index)
#define OFF_W     0      // 2*pi*f_k              (256)
#define OFF_WB    256    // 2*pi*(f_k+beat)       (256)
#define OFF_PHIM  512    // phi_m                 (256)
#define OFF_PHIB  768    // phi_b                 (256)
#define OFF_C1    1024   // -1/(48000*tau1)       (256)
#define OFF_C2    1280   // -1/(48000*tau2)       (256)
#define OFF_AA1   1536   // A0*a1                 (256)
#define OFF_AA2   1792   // A0*(1-a1)             (256)
#define OFF_POLE  2048
#define OFF_ALPHA 2052
#define OFF_AT    2056
#define OFF_FR    2060
#define OFF_WC    2064
#define OFF_PEAK  2068   // 4 x uint32 (atomicMax on abs-float bits)
#define OFF_HARM  2080   // harmonic, B*T floats
// total floats: 2080 + 576000 = 578,080 (~2.31 MB of d_ws)

static constexpr float  TWO_PI_F = 6.28318530717958647692f; // f32 0x40C90FDB
static constexpr double INV2PI_D = 0.15915494309189535;
static constexpr float  C_HI = (float)INV2PI_D;
static constexpr float  C_LO = (float)(INV2PI_D - (double)((float)INV2PI_D));

__device__ __forceinline__ uint32_t rotl32(uint32_t x, uint32_t n) {
    return (x << n) | (x >> (32u - n));
}

// threefry-2x32, 20 rounds, exactly as jax._src.prng.threefry2x32
__device__ __forceinline__ void tf2x32(uint32_t k0, uint32_t k1, uint32_t x0, uint32_t x1,
                                       uint32_t& o0, uint32_t& o1) {
    const uint32_t ks2 = k0 ^ k1 ^ 0x1BD11BDAu;
    x0 += k0; x1 += k1;
#define TF_RND(r) { x0 += x1; x1 = rotl32(x1, (r)); x1 ^= x0; }
    TF_RND(13) TF_RND(15) TF_RND(26) TF_RND(6)
    x0 += k1;  x1 += ks2 + 1u;
    TF_RND(17) TF_RND(29) TF_RND(16) TF_RND(24)
    x0 += ks2; x1 += k0 + 2u;
    TF_RND(13) TF_RND(15) TF_RND(26) TF_RND(6)
    x0 += k0;  x1 += k1 + 3u;
    TF_RND(17) TF_RND(29) TF_RND(16) TF_RND(24)
    x0 += k1;  x1 += ks2 + 4u;
    TF_RND(13) TF_RND(15) TF_RND(26) TF_RND(6)
    x0 += ks2; x1 += k0 + 5u;
#undef TF_RND
    o0 = x0; o1 = x1;
}

// pk = jax.random.split(jax.random.key(42), 3); partitionable scheme (validated r1)
__device__ __forceinline__ void get_keys(uint32_t pk[3][2]) {
    tf2x32(0u, 42u, 0u, 0u, pk[0][0], pk[0][1]);
    tf2x32(0u, 42u, 0u, 1u, pk[1][0], pk[1][1]);
    tf2x32(0u, 42u, 0u, 2u, pk[2][0], pk[2][1]);
}

__device__ __forceinline__ uint32_t bits_for(const uint32_t key[2], uint32_t idx) {
    uint32_t o0, o1;
    tf2x32(key[0], key[1], 0u, idx, o0, o1);
    return o0 ^ o1;
}

__device__ __forceinline__ float u01_from_bits(uint32_t bits) {
    return __fsub_rn(__uint_as_float((bits >> 9) | 0x3f800000u), 1.0f);
}

// XLA ErfInv32 (Giles) polynomial
__device__ float erfinv_xla_f32(float x) {
    float w = -log1pf(__fmul_rn(-x, x));
    float p;
    if (w < 5.0f) {
        w = __fsub_rn(w, 2.5f);
        p = 2.81022636e-08f;
        p = __fadd_rn(3.43273939e-07f,  __fmul_rn(p, w));
        p = __fadd_rn(-3.5233877e-06f,  __fmul_rn(p, w));
        p = __fadd_rn(-4.39150654e-06f, __fmul_rn(p, w));
        p = __fadd_rn(0.00021858087f,   __fmul_rn(p, w));
        p = __fadd_rn(-0.00125372503f,  __fmul_rn(p, w));
        p = __fadd_rn(-0.00417768164f,  __fmul_rn(p, w));
        p = __fadd_rn(0.246640727f,     __fmul_rn(p, w));
        p = __fadd_rn(1.50140941f,      __fmul_rn(p, w));
    } else {
        w = __fsub_rn(sqrtf(w), 3.0f);
        p = -0.000200214257f;
        p = __fadd_rn(0.000100950558f,  __fmul_rn(p, w));
        p = __fadd_rn(0.00134934322f,   __fmul_rn(p, w));
        p = __fadd_rn(-0.00367342844f,  __fmul_rn(p, w));
        p = __fadd_rn(0.00573950773f,   __fmul_rn(p, w));
        p = __fadd_rn(-0.0076224613f,   __fmul_rn(p, w));
        p = __fadd_rn(0.00943887047f,   __fmul_rn(p, w));
        p = __fadd_rn(1.00167406f,      __fmul_rn(p, w));
        p = __fadd_rn(2.83297682f,      __fmul_rn(p, w));
    }
    return __fmul_rn(p, x);
}

__device__ __forceinline__ float normal_from_bits(uint32_t bits) {
    const float LO = __uint_as_float(0xBF7FFFFFu); // nextafterf(-1, 0)
    float f = u01_from_bits(bits);
    float u = __fadd_rn(__fmul_rn(f, 2.0f), LO);
    u = fmaxf(u, LO);
    const float SQRT2_F = 1.41421356237309504880f;
    return __fmul_rn(SQRT2_F, erfinv_xla_f32(u));
}

// cos of an f32 radian arg (up to ~2^21): f32 Cody-Waite reduction (FMA two-product)
// + HW v_cos (input in revolutions). |reduction error| ~6e-8 rev -> cos err <~5e-7.
__device__ __forceinline__ float cosw(float arg) {
    float p = __fmul_rn(arg, C_HI);
    float e = fmaf(arg, C_HI, -p);            // exact tail of arg*C_HI
    float n = rintf(p);                       // exact (p < 2^18 < 2^24)
    float r = __fadd_rn(__fsub_rn(p, n), e);  // p-n exact by Sterbenz
    r = fmaf(arg, C_LO, r);
    return __builtin_amdgcn_cosf(r);
}

// ---------------- kernel 1: per-(b,k) params, phases, per-b scalars ----------------
__global__ void kprep(const float* __restrict__ B_inh, const float* __restrict__ f0_off,
                      const float* __restrict__ beat_hz, const float* __restrict__ noise,
                      const float* __restrict__ f0, const float* __restrict__ wfac,
                      const float* __restrict__ A0, const float* __restrict__ tau1,
                      const float* __restrict__ tau2, const float* __restrict__ a1,
                      float* __restrict__ ws) {
    int j = threadIdx.x;              // 0..255 = b*64 + k
    uint32_t pk[3][2];
    get_keys(pk);

    ws[OFF_PHIM + j] = __fmul_rn(u01_from_bits(bits_for(pk[0], (uint32_t)j)), TWO_PI_F);
    ws[OFF_PHIB + j] = __fmul_rn(u01_from_bits(bits_for(pk[1], (uint32_t)j)), TWO_PI_F);

    int b = j >> 6;
    int k = (j & 63) + 1;
    float x   = __fdiv_rn(f0_off[b], 1200.0f);
    float s   = (float)exp2((double)x);
    float f0a = __fmul_rn(f0[b], s);
    float sq  = sqrtf(__fadd_rn(1.0f, __fmul_rn(B_inh[b], (float)(k * k))));
    float fk  = __fmul_rn(__fmul_rn(f0a, (float)k), sq);
    float fkb = __fadd_rn(fk, beat_hz[j]);
    ws[OFF_W + j]  = __fmul_rn(TWO_PI_F, fk);
    ws[OFF_WB + j] = __fmul_rn(TWO_PI_F, fkb);

    ws[OFF_C1 + j]  = __fdiv_rn(-1.0f, __fmul_rn(48000.0f, tau1[j]));
    ws[OFF_C2 + j]  = __fdiv_rn(-1.0f, __fmul_rn(48000.0f, tau2[j]));
    float a1v = a1[j];
    ws[OFF_AA1 + j] = __fmul_rn(A0[j], a1v);
    ws[OFF_AA2 + j] = __fmul_rn(A0[j], __fsub_rn(1.0f, a1v));

    if (j < B_BATCH) {
        float at  = fmaxf(noise[j * 4 + 0], 0.002f);
        float fr  = noise[j * 4 + 1];
        float cen = noise[j * 4 + 2];
        float lr  = (float)log2(24000.0 / 27.5);
        float y   = __fmul_rn(cen, lr);
        float e   = (float)exp2((double)y);
        float v   = __fdiv_rn(__fmul_rn(27.5f, e), 24000.0f);
        float cut = fminf(fmaxf(v, 0.01f), 0.99f);
        float pole = expf(__fmul_rn(-TWO_PI_F, cut));
        ws[OFF_POLE + j]  = pole;
        ws[OFF_ALPHA + j] = __fsub_rn(1.0f, pole);
        ws[OFF_AT + j] = at;
        ws[OFF_FR + j] = fr;
        ws[OFF_WC + j] = fminf(fmaxf(wfac[j], 0.0f), 2.0f);
        ((unsigned int*)ws)[OFF_PEAK + j] = 0u;   // re-init every call (determinism)
    }
}

// ---------------- kernel 2: harmonic sum + per-batch abs-peak (1 sample/thread) ----
__global__ void __launch_bounds__(256, 6)
kharm(const float* __restrict__ prm,        // ws (param block, read-only)
      const float* __restrict__ bd,         // beat_depth input
      float* __restrict__ harm,             // ws + OFF_HARM
      unsigned int* __restrict__ peak) {    // ws + OFF_PEAK
    int t = blockIdx.x * blockDim.x + threadIdx.x;
    int b = blockIdx.y;
    if (t >= T_TOT) return;
    const float* w    = prm + OFF_W    + (b << 6);
    const float* wb   = prm + OFF_WB   + (b << 6);
    const float* phim = prm + OFF_PHIM + (b << 6);
    const float* phib = prm + OFF_PHIB + (b << 6);
    const float* c1a  = prm + OFF_C1   + (b << 6);
    const float* c2a  = prm + OFF_C2   + (b << 6);
    const float* aa1  = prm + OFF_AA1  + (b << 6);
    const float* aa2  = prm + OFF_AA2  + (b << 6);
    const float* bdp  = bd + (b << 6);

    float fn = (float)t;
    float tt = __fdiv_rn(fn, 48000.0f);     // bit-exact fl(t/48000)
    float acc0 = 0.0f, acc1 = 0.0f;

#pragma unroll 4
    for (int k = 0; k < K_HARM; ++k) {
        float wk = w[k], wbk = wb[k], pm = phim[k], pb = phib[k];
        float c1 = c1a[k], c2 = c2a[k], A1 = aa1[k], A2 = aa2[k], bdk = bdp[k];

        float am = __fadd_rn(__fmul_rn(wk,  tt), pm);   // bit-identical f32 arg
        float ab = __fadd_rn(__fmul_rn(wbk, tt), pb);
        float cm = cosw(am);
        float cb = cosw(ab);
        float e1 = __expf(fn * c1);
        float e2 = __expf(fn * c2);
        float env = fmaf(A1, e1, __fmul_rn(A2, e2));
        float osc = fmaf(bdk, cb, cm);
        if (k & 1) acc1 = fmaf(env, osc, acc1);
        else       acc0 = fmaf(env, osc, acc0);
    }
    float acc = __fadd_rn(acc0, acc1);
    harm[b * T_TOT + t] = acc;

    // wave-level max reduce, 1 atomic per wave
    float m = fabsf(acc);
#pragma unroll
    for (int off = 32; off > 0; off >>= 1)
        m = fmaxf(m, __shfl_xor(m, off));
    if ((threadIdx.x & 63) == 0)
        atomicMax(&peak[b], __float_as_uint(m));
}

// ---------------- kernel 3: white-noise gen + windowed IIR + epilogue --------------
#define SPT   4
#define CHUNK 1024                       // 256 threads * SPT
#define WIN   (CHUNK + WF - 1)           // 1151
#define WPAD  (WIN + ((WIN + 31) >> 5))  // +idx/32 swizzle pad

__global__ void kfinal(const float* __restrict__ ws, float* __restrict__ out) {
    __shared__ __align__(16) float s[WPAD];
    __shared__ __align__(16) float ptab[WF];
    const int b   = blockIdx.y;
    const int t0  = blockIdx.x * CHUNK;
    const int tid = threadIdx.x;

    const float alpha = ws[OFF_ALPHA + b];
    const float pole  = ws[OFF_POLE + b];
    const float at    = ws[OFF_AT + b];
    const float fr    = ws[OFF_FR + b];
    const float wcf   = ws[OFF_WC + b];
    const float peak  = fmaxf(__uint_as_float(((const unsigned int*)ws)[OFF_PEAK + b]), 1e-6f);
    const float cpk   = __fdiv_rn(0.9f, peak);

    uint32_t k2a, k2b;
    tf2x32(0u, 42u, 0u, 2u, k2a, k2b);   // pk[2]

    // stage aw window [t0-127, t0+CHUNK) into swizzled LDS (generated, not loaded)
    for (int idx = tid; idx < WIN; idx += 256) {
        int j = t0 - (WF - 1) + idx;
        float v = 0.0f;
        if (j >= 0 && j < T_TOT) {
            uint32_t o0, o1;
            tf2x32(k2a, k2b, 0u, (uint32_t)(b * T_TOT + j), o0, o1);
            v = __fmul_rn(alpha, normal_from_bits(o0 ^ o1));
        }
        s[idx + (idx >> 5)] = v;
    }
    if (tid < WF) ptab[tid] = exp2f((float)tid * log2f(pole));   // pole^tid
    __syncthreads();

    int t = t0 + tid * SPT;
    if (t >= N_SAMP) return;
    const float p128 = __fmul_rn(ptab[WF - 1], pole);   // pole^WF
    const int base = tid * SPT + (WF - 1);              // s-index of aw[t]

    // filt[t] = sum_{i<WF} pole^i * aw[t-i]
    float f0 = 0.f, f1 = 0.f, f2 = 0.f, f3 = 0.f;
#pragma unroll
    for (int i = 0; i < WF; i += 4) {
        float4 pv = *(const float4*)&ptab[i];
        int a0 = base - i, a1i = a0 - 1, a2i = a0 - 2, a3i = a0 - 3;
        f0 = fmaf(pv.x, s[a0  + (a0  >> 5)], f0);
        f1 = fmaf(pv.y, s[a1i + (a1i >> 5)], f1);
        f2 = fmaf(pv.z, s[a2i + (a2i >> 5)], f2);
        f3 = fmaf(pv.w, s[a3i + (a3i >> 5)], f3);
    }
    float filt = __fadd_rn(__fadd_rn(f0, f2), __fadd_rn(f1, f3));

    const float* harm = ws + OFF_HARM + b * T_TOT;
    float* outL = out + (b * 2 + 0) * N_SAMP;
    float* outR = out + (b * 2 + 1) * N_SAMP;

#pragma unroll
    for (int jj = 0; jj < SPT; ++jj) {
        int tj = t + jj;
        if (tj >= N_SAMP) break;
        if (jj > 0) {
            // filt[t+1] = pole*filt[t] + aw[t+1] - pole^WF * aw[t+1-WF]  (exact identity)
            int bn = base + jj;
            int bo = bn - WF;
            filt = fmaf(pole, filt, s[bn + (bn >> 5)]);
            filt = fmaf(-p128, s[bo + (bo >> 5)], filt);
        }
        float fnf = (float)tj;
        float tt  = __fdiv_rn(fnf, 48000.0f);
        float hn  = __fmul_rn(harm[tj], cpk);
        float ne  = __fmul_rn(__expf(__fdiv_rn(-tt, at)), fr);
        float ns  = __fmul_rn(filt, ne);
        float mono = __fadd_rn(hn, ns);
        float side = __fmul_rn(__fmul_rn(mono, wcf), 0.3f);
        outL[tj] = fminf(fmaxf(__fadd_rn(mono, side), -1.0f), 1.0f);
        outR[tj] = fminf(fmaxf(__fsub_rn(mono, side), -1.0f), 1.0f);
    }
}

extern "C" void kernel_launch(void* const* d_in, const int* in_sizes, int n_in,
                              void* d_out, int out_size, void* d_ws, size_t ws_size,
                              hipStream_t stream) {
    (void)in_sizes; (void)n_in; (void)out_size; (void)ws_size;
    const float* B_inh   = (const float*)d_in[0];
    const float* f0_off  = (const float*)d_in[1];
    const float* A0      = (const float*)d_in[2];
    const float* tau1    = (const float*)d_in[3];
    const float* tau2    = (const float*)d_in[4];
    const float* a1      = (const float*)d_in[5];
    const float* beat_hz = (const float*)d_in[6];
    const float* beat_dp = (const float*)d_in[7];
    const float* noise   = (const float*)d_in[8];
    const float* f0      = (const float*)d_in[9];
    const float* wfac    = (const float*)d_in[10];
    float* out = (float*)d_out;
    float* ws  = (float*)d_ws;

    kprep<<<dim3(1), dim3(256), 0, stream>>>(B_inh, f0_off, beat_hz, noise, f0, wfac,
                                             A0, tau1, tau2, a1, ws);

    dim3 gh((T_TOT + 255) / 256, B_BATCH);
    kharm<<<gh, dim3(256), 0, stream>>>(ws, beat_dp, ws + OFF_HARM,
                                        (unsigned int*)ws + OFF_PEAK);

    dim3 gf((N_SAMP + CHUNK - 1) / CHUNK, B_BATCH);
    kfinal<<<gf, dim3(256), 0, stream>>>(ws, out);
}

// Round 4
// 87.341 us; speedup vs baseline: 1.4977x; 1.4977x over previous
//
#include <hip/hip_runtime.h>
#include <stdint.h>
#include <math.h>

#pragma clang fp contract(off)

#define B_BATCH 4
#define K_HARM  64
#define T_TOT   144000   // ceil(3*48000/240)*240 == 3*48000
#define N_SAMP  144000
#define WF      128      // pole<=0.93937 -> pole^128 ~ 3e-4; *noise_env(<=0.011) -> <2e-6 abs

// ws layout (float index)
// packed per-(b,k) params, stride 16 floats (64B): fields
//   0:w  1:wb  2:phim  3:phib  4:c1'  5:c2'  6:A1  7:A2  8:bd  (9..15 pad)
#define OFF_PK    0
#define PK_STRIDE 16
#define OFF_POLE  4096
#define OFF_ALPHA 4100
#define OFF_AT    4104
#define OFF_FR    4108
#define OFF_WC    4112
#define OFF_PEAK  4116   // 4 x uint32 (atomicMax on abs-float bits)
#define OFF_HARM  4128   // harmonic, B*T floats
// total floats: 4128 + 576000 = 580,128 (~2.32 MB of d_ws)

static constexpr float  TWO_PI_F = 6.28318530717958647692f; // f32 0x40C90FDB
static constexpr double INV2PI_D = 0.15915494309189535;
static constexpr float  C_HI = (float)INV2PI_D;
static constexpr float  C_LO = (float)(INV2PI_D - (double)((float)INV2PI_D));
static constexpr float  LOG2E_F = 1.44269504088896340736f;

__device__ __forceinline__ uint32_t rotl32(uint32_t x, uint32_t n) {
    return (x << n) | (x >> (32u - n));
}

// threefry-2x32, 20 rounds, exactly as jax._src.prng.threefry2x32
__device__ __forceinline__ void tf2x32(uint32_t k0, uint32_t k1, uint32_t x0, uint32_t x1,
                                       uint32_t& o0, uint32_t& o1) {
    const uint32_t ks2 = k0 ^ k1 ^ 0x1BD11BDAu;
    x0 += k0; x1 += k1;
#define TF_RND(r) { x0 += x1; x1 = rotl32(x1, (r)); x1 ^= x0; }
    TF_RND(13) TF_RND(15) TF_RND(26) TF_RND(6)
    x0 += k1;  x1 += ks2 + 1u;
    TF_RND(17) TF_RND(29) TF_RND(16) TF_RND(24)
    x0 += ks2; x1 += k0 + 2u;
    TF_RND(13) TF_RND(15) TF_RND(26) TF_RND(6)
    x0 += k0;  x1 += k1 + 3u;
    TF_RND(17) TF_RND(29) TF_RND(16) TF_RND(24)
    x0 += k1;  x1 += ks2 + 4u;
    TF_RND(13) TF_RND(15) TF_RND(26) TF_RND(6)
    x0 += ks2; x1 += k0 + 5u;
#undef TF_RND
    o0 = x0; o1 = x1;
}

// pk = jax.random.split(jax.random.key(42), 3); partitionable scheme (validated r1)
__device__ __forceinline__ void get_keys(uint32_t pk[3][2]) {
    tf2x32(0u, 42u, 0u, 0u, pk[0][0], pk[0][1]);
    tf2x32(0u, 42u, 0u, 1u, pk[1][0], pk[1][1]);
    tf2x32(0u, 42u, 0u, 2u, pk[2][0], pk[2][1]);
}

__device__ __forceinline__ uint32_t bits_for(const uint32_t key[2], uint32_t idx) {
    uint32_t o0, o1;
    tf2x32(key[0], key[1], 0u, idx, o0, o1);
    return o0 ^ o1;
}

__device__ __forceinline__ float u01_from_bits(uint32_t bits) {
    return __fsub_rn(__uint_as_float((bits >> 9) | 0x3f800000u), 1.0f);
}

// XLA ErfInv32 (Giles) polynomial
__device__ float erfinv_xla_f32(float x) {
    float w = -log1pf(__fmul_rn(-x, x));
    float p;
    if (w < 5.0f) {
        w = __fsub_rn(w, 2.5f);
        p = 2.81022636e-08f;
        p = __fadd_rn(3.43273939e-07f,  __fmul_rn(p, w));
        p = __fadd_rn(-3.5233877e-06f,  __fmul_rn(p, w));
        p = __fadd_rn(-4.39150654e-06f, __fmul_rn(p, w));
        p = __fadd_rn(0.00021858087f,   __fmul_rn(p, w));
        p = __fadd_rn(-0.00125372503f,  __fmul_rn(p, w));
        p = __fadd_rn(-0.00417768164f,  __fmul_rn(p, w));
        p = __fadd_rn(0.246640727f,     __fmul_rn(p, w));
        p = __fadd_rn(1.50140941f,      __fmul_rn(p, w));
    } else {
        w = __fsub_rn(sqrtf(w), 3.0f);
        p = -0.000200214257f;
        p = __fadd_rn(0.000100950558f,  __fmul_rn(p, w));
        p = __fadd_rn(0.00134934322f,   __fmul_rn(p, w));
        p = __fadd_rn(-0.00367342844f,  __fmul_rn(p, w));
        p = __fadd_rn(0.00573950773f,   __fmul_rn(p, w));
        p = __fadd_rn(-0.0076224613f,   __fmul_rn(p, w));
        p = __fadd_rn(0.00943887047f,   __fmul_rn(p, w));
        p = __fadd_rn(1.00167406f,      __fmul_rn(p, w));
        p = __fadd_rn(2.83297682f,      __fmul_rn(p, w));
    }
    return __fmul_rn(p, x);
}

__device__ __forceinline__ float normal_from_bits(uint32_t bits) {
    const float LO = __uint_as_float(0xBF7FFFFFu); // nextafterf(-1, 0)
    float f = u01_from_bits(bits);
    float u = __fadd_rn(__fmul_rn(f, 2.0f), LO);
    u = fmaxf(u, LO);
    const float SQRT2_F = 1.41421356237309504880f;
    return __fmul_rn(SQRT2_F, erfinv_xla_f32(u));
}

// cos of an f32 radian arg (up to ~2^21): f32 Cody-Waite reduction (FMA two-product)
// + HW v_cos (input in revolutions). Validated r3 (absmax 0.0100).
__device__ __forceinline__ float cosw(float arg) {
    float p = __fmul_rn(arg, C_HI);
    float e = fmaf(arg, C_HI, -p);            // exact tail of arg*C_HI
    float n = rintf(p);                       // exact (p < 2^18 < 2^24)
    float r = __fadd_rn(__fsub_rn(p, n), e);  // p-n exact by Sterbenz
    r = fmaf(arg, C_LO, r);
    return __builtin_amdgcn_cosf(r);
}

// ---------------- kernel 1: per-(b,k) params, phases, per-b scalars ----------------
__global__ void kprep(const float* __restrict__ B_inh, const float* __restrict__ f0_off,
                      const float* __restrict__ beat_hz, const float* __restrict__ noise,
                      const float* __restrict__ f0, const float* __restrict__ wfac,
                      const float* __restrict__ A0, const float* __restrict__ tau1,
                      const float* __restrict__ tau2, const float* __restrict__ a1,
                      const float* __restrict__ bd,
                      float* __restrict__ ws) {
    int j = threadIdx.x;              // 0..255 = b*64 + k
    uint32_t pk[3][2];
    get_keys(pk);

    float phim = __fmul_rn(u01_from_bits(bits_for(pk[0], (uint32_t)j)), TWO_PI_F);
    float phib = __fmul_rn(u01_from_bits(bits_for(pk[1], (uint32_t)j)), TWO_PI_F);

    int b = j >> 6;
    int k = (j & 63) + 1;
    float x   = __fdiv_rn(f0_off[b], 1200.0f);
    float s   = (float)exp2((double)x);
    float f0a = __fmul_rn(f0[b], s);
    float sq  = sqrtf(__fadd_rn(1.0f, __fmul_rn(B_inh[b], (float)(k * k))));
    float fk  = __fmul_rn(__fmul_rn(f0a, (float)k), sq);
    float fkb = __fadd_rn(fk, beat_hz[j]);

    float* P = ws + OFF_PK + j * PK_STRIDE;
    P[0] = __fmul_rn(TWO_PI_F, fk);
    P[1] = __fmul_rn(TWO_PI_F, fkb);
    P[2] = phim;
    P[3] = phib;
    // exp2-domain envelope rates: c' = -log2(e)/(48000*tau)
    P[4] = __fdiv_rn(-LOG2E_F, __fmul_rn(48000.0f, tau1[j]));
    P[5] = __fdiv_rn(-LOG2E_F, __fmul_rn(48000.0f, tau2[j]));
    float a1v = a1[j];
    P[6] = __fmul_rn(A0[j], a1v);
    P[7] = __fmul_rn(A0[j], __fsub_rn(1.0f, a1v));
    P[8] = bd[j];

    if (j < B_BATCH) {
        float at  = fmaxf(noise[j * 4 + 0], 0.002f);
        float fr  = noise[j * 4 + 1];
        float cen = noise[j * 4 + 2];
        float lr  = (float)log2(24000.0 / 27.5);
        float y   = __fmul_rn(cen, lr);
        float e   = (float)exp2((double)y);
        float v   = __fdiv_rn(__fmul_rn(27.5f, e), 24000.0f);
        float cut = fminf(fmaxf(v, 0.01f), 0.99f);
        float pole = expf(__fmul_rn(-TWO_PI_F, cut));
        ws[OFF_POLE + j]  = pole;
        ws[OFF_ALPHA + j] = __fsub_rn(1.0f, pole);
        ws[OFF_AT + j] = at;
        ws[OFF_FR + j] = fr;
        ws[OFF_WC + j] = fminf(fmaxf(wfac[j], 0.0f), 2.0f);
        ((unsigned int*)ws)[OFF_PEAK + j] = 0u;   // re-init every call (determinism)
    }
}

// ---------------- kernel 2: harmonic sum + per-batch abs-peak (2 samples/thread) ---
__global__ void kharm(const float* __restrict__ prm,        // ws (param block, read-only)
                      float* __restrict__ harm,             // ws + OFF_HARM
                      unsigned int* __restrict__ peak) {    // ws + OFF_PEAK
    int gid = blockIdx.x * blockDim.x + threadIdx.x;
    int b = blockIdx.y;
    int t0 = gid * 2;
    if (t0 >= T_TOT) return;

    float fn0 = (float)t0;
    float fn1 = (float)(t0 + 1);
    float tt0 = __fdiv_rn(fn0, 48000.0f);   // bit-exact fl(t/48000)
    float tt1 = __fdiv_rn(fn1, 48000.0f);
    float acc0 = 0.0f, acc1 = 0.0f;

    const float* Pb = prm + OFF_PK + (b << 6) * PK_STRIDE;

#pragma unroll 8
    for (int k = 0; k < K_HARM; ++k) {
        const float* P = Pb + k * PK_STRIDE;   // uniform addr -> wide s_load
        float wk = P[0], wbk = P[1], pm = P[2], pb = P[3];
        float c1 = P[4], c2 = P[5], A1 = P[6], A2 = P[7], bdk = P[8];

        // sample t0
        {
            float am = __fadd_rn(__fmul_rn(wk,  tt0), pm);   // bit-identical f32 arg
            float ab = __fadd_rn(__fmul_rn(wbk, tt0), pb);
            float cm = cosw(am);
            float cb = cosw(ab);
            float e1 = __builtin_amdgcn_exp2f(__fmul_rn(fn0, c1));
            float e2 = __builtin_amdgcn_exp2f(__fmul_rn(fn0, c2));
            float env = fmaf(A1, e1, __fmul_rn(A2, e2));
            acc0 = fmaf(env, fmaf(bdk, cb, cm), acc0);
        }
        // sample t0+1
        {
            float am = __fadd_rn(__fmul_rn(wk,  tt1), pm);
            float ab = __fadd_rn(__fmul_rn(wbk, tt1), pb);
            float cm = cosw(am);
            float cb = cosw(ab);
            float e1 = __builtin_amdgcn_exp2f(__fmul_rn(fn1, c1));
            float e2 = __builtin_amdgcn_exp2f(__fmul_rn(fn1, c2));
            float env = fmaf(A1, e1, __fmul_rn(A2, e2));
            acc1 = fmaf(env, fmaf(bdk, cb, cm), acc1);
        }
    }
    *(float2*)(harm + b * T_TOT + t0) = make_float2(acc0, acc1);

    // wave-level max reduce, 1 atomic per wave
    float m = fmaxf(fabsf(acc0), fabsf(acc1));
#pragma unroll
    for (int off = 32; off > 0; off >>= 1)
        m = fmaxf(m, __shfl_xor(m, off));
    if ((threadIdx.x & 63) == 0)
        atomicMax(&peak[b], __float_as_uint(m));
}

// ---------------- kernel 3: white-noise gen + windowed IIR + epilogue --------------
#define SPT   4
#define CHUNK 1024                       // 256 threads * SPT
#define WIN   (CHUNK + WF - 1)           // 1151
#define WPAD  (WIN + ((WIN + 31) >> 5))  // +idx/32 swizzle pad

__global__ void kfinal(const float* __restrict__ ws, float* __restrict__ out) {
    __shared__ __align__(16) float s[WPAD];
    __shared__ __align__(16) float ptab[WF];
    const int b   = blockIdx.y;
    const int t0  = blockIdx.x * CHUNK;
    const int tid = threadIdx.x;

    const float alpha = ws[OFF_ALPHA + b];
    const float pole  = ws[OFF_POLE + b];
    const float at    = ws[OFF_AT + b];
    const float fr    = ws[OFF_FR + b];
    const float wcf   = ws[OFF_WC + b];
    const float peak  = fmaxf(__uint_as_float(((const unsigned int*)ws)[OFF_PEAK + b]), 1e-6f);
    const float cpk   = __fdiv_rn(0.9f, peak);

    uint32_t k2a, k2b;
    tf2x32(0u, 42u, 0u, 2u, k2a, k2b);   // pk[2]

    // stage aw window [t0-127, t0+CHUNK) into swizzled LDS (generated, not loaded)
    for (int idx = tid; idx < WIN; idx += 256) {
        int j = t0 - (WF - 1) + idx;
        float v = 0.0f;
        if (j >= 0 && j < T_TOT) {
            uint32_t o0, o1;
            tf2x32(k2a, k2b, 0u, (uint32_t)(b * T_TOT + j), o0, o1);
            v = __fmul_rn(alpha, normal_from_bits(o0 ^ o1));
        }
        s[idx + (idx >> 5)] = v;
    }
    if (tid < WF) ptab[tid] = exp2f((float)tid * log2f(pole));   // pole^tid
    __syncthreads();

    int t = t0 + tid * SPT;
    if (t >= N_SAMP) return;
    const float p128 = __fmul_rn(ptab[WF - 1], pole);   // pole^WF
    const int base = tid * SPT + (WF - 1);              // s-index of aw[t]

    // filt[t] = sum_{i<WF} pole^i * aw[t-i]
    float f0 = 0.f, f1 = 0.f, f2 = 0.f, f3 = 0.f;
#pragma unroll
    for (int i = 0; i < WF; i += 4) {
        float4 pv = *(const float4*)&ptab[i];
        int a0 = base - i, a1i = a0 - 1, a2i = a0 - 2, a3i = a0 - 3;
        f0 = fmaf(pv.x, s[a0  + (a0  >> 5)], f0);
        f1 = fmaf(pv.y, s[a1i + (a1i >> 5)], f1);
        f2 = fmaf(pv.z, s[a2i + (a2i >> 5)], f2);
        f3 = fmaf(pv.w, s[a3i + (a3i >> 5)], f3);
    }
    float filt = __fadd_rn(__fadd_rn(f0, f2), __fadd_rn(f1, f3));

    const float* harm = ws + OFF_HARM + b * T_TOT;
    float* outL = out + (b * 2 + 0) * N_SAMP;
    float* outR = out + (b * 2 + 1) * N_SAMP;

#pragma unroll
    for (int jj = 0; jj < SPT; ++jj) {
        int tj = t + jj;
        if (tj >= N_SAMP) break;
        if (jj > 0) {
            // filt[t+1] = pole*filt[t] + aw[t+1] - pole^WF * aw[t+1-WF]  (exact identity)
            int bn = base + jj;
            int bo = bn - WF;
            filt = fmaf(pole, filt, s[bn + (bn >> 5)]);
            filt = fmaf(-p128, s[bo + (bo >> 5)], filt);
        }
        float fnf = (float)tj;
        float tt  = __fdiv_rn(fnf, 48000.0f);
        float hn  = __fmul_rn(harm[tj], cpk);
        float ne  = __fmul_rn(__expf(__fdiv_rn(-tt, at)), fr);
        float ns  = __fmul_rn(filt, ne);
        float mono = __fadd_rn(hn, ns);
        float side = __fmul_rn(__fmul_rn(mono, wcf), 0.3f);
        outL[tj] = fminf(fmaxf(__fadd_rn(mono, side), -1.0f), 1.0f);
        outR[tj] = fminf(fmaxf(__fsub_rn(mono, side), -1.0f), 1.0f);
    }
}

extern "C" void kernel_launch(void* const* d_in, const int* in_sizes, int n_in,
                              void* d_out, int out_size, void* d_ws, size_t ws_size,
                              hipStream_t stream) {
    (void)in_sizes; (void)n_in; (void)out_size; (void)ws_size;
    const float* B_inh   = (const float*)d_in[0];
    const float* f0_off  = (const float*)d_in[1];
    const float* A0      = (const float*)d_in[2];
    const float* tau1    = (const float*)d_in[3];
    const float* tau2    = (const float*)d_in[4];
    const float* a1      = (const float*)d_in[5];
    const float* beat_hz = (const float*)d_in[6];
    const float* beat_dp = (const float*)d_in[7];
    const float* noise   = (const float*)d_in[8];
    const float* f0      = (const float*)d_in[9];
    const float* wfac    = (const float*)d_in[10];
    float* out = (float*)d_out;
    float* ws  = (float*)d_ws;

    kprep<<<dim3(1), dim3(256), 0, stream>>>(B_inh, f0_off, beat_hz, noise, f0, wfac,
                                             A0, tau1, tau2, a1, beat_dp, ws);

    dim3 gh((T_TOT / 2 + 255) / 256, B_BATCH);
    kharm<<<gh, dim3(256), 0, stream>>>(ws, ws + OFF_HARM,
                                        (unsigned int*)ws + OFF_PEAK);

    dim3 gf((N_SAMP + CHUNK - 1) / CHUNK, B_BATCH);
    kfinal<<<gf, dim3(256), 0, stream>>>(ws, out);
}

// Round 5
// 38.215 us; speedup vs baseline: 3.4231x; 2.2855x over previous
//
#include <hip/hip_runtime.h>
#include <stdint.h>
#include <math.h>

#pragma clang fp contract(off)

#define B_BATCH 4
#define K_HARM  64
#define T_TOT   144000   // ceil(3*48000/240)*240 == 3*48000
#define N_SAMP  144000
#define WF      128      // pole<=0.93937 -> pole^128 ~ 3e-4; *noise_env(<=0.011) -> <2e-6 abs

// ws layout (float index)
// packed per-(b,k) params, stride 16 floats (64B):
//   0:w  1:wb  2:phim  3:phib  4:c1'  5:c2'  6:A1  7:A2  8:bd
//   9:cd 10:sd 11:cbd 12:sbd 13:d1 14:d2   (15 pad)
#define OFF_PK    0
#define PK_STRIDE 16
#define OFF_POLE  4096
#define OFF_ALPHA 4100
#define OFF_AT    4104
#define OFF_FR    4108
#define OFF_WC    4112
#define OFF_PEAK  4116   // 4 x uint32 (atomicMax on abs-float bits)
#define OFF_HARM  4128   // harmonic, B*T floats
// total floats: 4128 + 576000 = 580,128 (~2.32 MB of d_ws)

static constexpr float  TWO_PI_F = 6.28318530717958647692f; // f32 0x40C90FDB
static constexpr double INV2PI_D = 0.15915494309189535;
static constexpr float  C_HI = (float)INV2PI_D;
static constexpr float  C_LO = (float)(INV2PI_D - (double)((float)INV2PI_D));
static constexpr float  LOG2E_F = 1.44269504088896340736f;
static constexpr float  LN2_F   = 0.69314718055994530942f;

__device__ __forceinline__ uint32_t rotl32(uint32_t x, uint32_t n) {
    return (x << n) | (x >> (32u - n));
}

// threefry-2x32, 20 rounds, exactly as jax._src.prng.threefry2x32
__device__ __forceinline__ void tf2x32(uint32_t k0, uint32_t k1, uint32_t x0, uint32_t x1,
                                       uint32_t& o0, uint32_t& o1) {
    const uint32_t ks2 = k0 ^ k1 ^ 0x1BD11BDAu;
    x0 += k0; x1 += k1;
#define TF_RND(r) { x0 += x1; x1 = rotl32(x1, (r)); x1 ^= x0; }
    TF_RND(13) TF_RND(15) TF_RND(26) TF_RND(6)
    x0 += k1;  x1 += ks2 + 1u;
    TF_RND(17) TF_RND(29) TF_RND(16) TF_RND(24)
    x0 += ks2; x1 += k0 + 2u;
    TF_RND(13) TF_RND(15) TF_RND(26) TF_RND(6)
    x0 += k0;  x1 += k1 + 3u;
    TF_RND(17) TF_RND(29) TF_RND(16) TF_RND(24)
    x0 += k1;  x1 += ks2 + 4u;
    TF_RND(13) TF_RND(15) TF_RND(26) TF_RND(6)
    x0 += ks2; x1 += k0 + 5u;
#undef TF_RND
    o0 = x0; o1 = x1;
}

// pk = jax.random.split(jax.random.key(42), 3); partitionable scheme (validated r1)
__device__ __forceinline__ void get_keys(uint32_t pk[3][2]) {
    tf2x32(0u, 42u, 0u, 0u, pk[0][0], pk[0][1]);
    tf2x32(0u, 42u, 0u, 1u, pk[1][0], pk[1][1]);
    tf2x32(0u, 42u, 0u, 2u, pk[2][0], pk[2][1]);
}

__device__ __forceinline__ uint32_t bits_for(const uint32_t key[2], uint32_t idx) {
    uint32_t o0, o1;
    tf2x32(key[0], key[1], 0u, idx, o0, o1);
    return o0 ^ o1;
}

__device__ __forceinline__ float u01_from_bits(uint32_t bits) {
    return __fsub_rn(__uint_as_float((bits >> 9) | 0x3f800000u), 1.0f);
}

// XLA ErfInv32 (Giles) polynomial; log1p(-x^2) via HW v_log (noise path:
// rel-err budget ~1e-4, this delivers ~1e-6)
__device__ __forceinline__ float erfinv_fast(float x) {
    float v = fmaf(-x, x, 1.0f);                       // 1 - x^2 (exact-ish)
    float w = __fmul_rn(-LN2_F, __builtin_amdgcn_logf(v));  // -ln(1-x^2)
    float p;
    if (w < 5.0f) {
        w = __fsub_rn(w, 2.5f);
        p = 2.81022636e-08f;
        p = fmaf(p, w, 3.43273939e-07f);
        p = fmaf(p, w, -3.5233877e-06f);
        p = fmaf(p, w, -4.39150654e-06f);
        p = fmaf(p, w, 0.00021858087f);
        p = fmaf(p, w, -0.00125372503f);
        p = fmaf(p, w, -0.00417768164f);
        p = fmaf(p, w, 0.246640727f);
        p = fmaf(p, w, 1.50140941f);
    } else {
        w = __fsub_rn(sqrtf(w), 3.0f);
        p = -0.000200214257f;
        p = fmaf(p, w, 0.000100950558f);
        p = fmaf(p, w, 0.00134934322f);
        p = fmaf(p, w, -0.00367342844f);
        p = fmaf(p, w, 0.00573950773f);
        p = fmaf(p, w, -0.0076224613f);
        p = fmaf(p, w, 0.00943887047f);
        p = fmaf(p, w, 1.00167406f);
        p = fmaf(p, w, 2.83297682f);
    }
    return __fmul_rn(p, x);
}

__device__ __forceinline__ float normal_from_bits(uint32_t bits) {
    const float LO = __uint_as_float(0xBF7FFFFFu); // nextafterf(-1, 0)
    float f = u01_from_bits(bits);
    float u = __fadd_rn(__fmul_rn(f, 2.0f), LO);
    u = fmaxf(u, LO);
    const float SQRT2_F = 1.41421356237309504880f;
    return __fmul_rn(SQRT2_F, erfinv_fast(u));
}

// f32 Cody-Waite: radians -> reduced revolutions in [-0.5, 0.5]
__device__ __forceinline__ float reduce_rev(float arg) {
    float p = __fmul_rn(arg, C_HI);
    float e = fmaf(arg, C_HI, -p);            // exact tail of arg*C_HI
    float n = rintf(p);                       // exact (p < 2^18 < 2^24)
    float r = __fadd_rn(__fsub_rn(p, n), e);  // p-n exact by Sterbenz
    return fmaf(arg, C_LO, r);
}

// ---------------- kernel 1: per-(b,k) params, phases, per-b scalars ----------------
__global__ void kprep(const float* __restrict__ B_inh, const float* __restrict__ f0_off,
                      const float* __restrict__ beat_hz, const float* __restrict__ noise,
                      const float* __restrict__ f0, const float* __restrict__ wfac,
                      const float* __restrict__ A0, const float* __restrict__ tau1,
                      const float* __restrict__ tau2, const float* __restrict__ a1,
                      const float* __restrict__ bd,
                      float* __restrict__ ws) {
    int j = threadIdx.x;              // 0..255 = b*64 + k
    uint32_t pk[3][2];
    get_keys(pk);

    float phim = __fmul_rn(u01_from_bits(bits_for(pk[0], (uint32_t)j)), TWO_PI_F);
    float phib = __fmul_rn(u01_from_bits(bits_for(pk[1], (uint32_t)j)), TWO_PI_F);

    int b = j >> 6;
    int k = (j & 63) + 1;
    float x   = __fdiv_rn(f0_off[b], 1200.0f);
    float s   = (float)exp2((double)x);
    float f0a = __fmul_rn(f0[b], s);
    float sq  = sqrtf(__fadd_rn(1.0f, __fmul_rn(B_inh[b], (float)(k * k))));
    float fk  = __fmul_rn(__fmul_rn(f0a, (float)k), sq);
    float fkb = __fadd_rn(fk, beat_hz[j]);

    float w_  = __fmul_rn(TWO_PI_F, fk);
    float wb_ = __fmul_rn(TWO_PI_F, fkb);
    float c1  = __fdiv_rn(-LOG2E_F, __fmul_rn(48000.0f, tau1[j]));
    float c2  = __fdiv_rn(-LOG2E_F, __fmul_rn(48000.0f, tau2[j]));

    float* P = ws + OFF_PK + j * PK_STRIDE;
    P[0] = w_;
    P[1] = wb_;
    P[2] = phim;
    P[3] = phib;
    P[4] = c1;
    P[5] = c2;
    float a1v = a1[j];
    P[6] = __fmul_rn(A0[j], a1v);
    P[7] = __fmul_rn(A0[j], __fsub_rn(1.0f, a1v));
    P[8] = bd[j];
    // rotation / decay step constants (f64 once, exact-ish)
    double dth  = (double)w_  / 48000.0;
    double dthb = (double)wb_ / 48000.0;
    P[9]  = (float)cos(dth);
    P[10] = (float)sin(dth);
    P[11] = (float)cos(dthb);
    P[12] = (float)sin(dthb);
    P[13] = (float)exp2((double)c1);
    P[14] = (float)exp2((double)c2);

    if (j < B_BATCH) {
        float at  = fmaxf(noise[j * 4 + 0], 0.002f);
        float fr  = noise[j * 4 + 1];
        float cen = noise[j * 4 + 2];
        float lr  = (float)log2(24000.0 / 27.5);
        float y   = __fmul_rn(cen, lr);
        float e   = (float)exp2((double)y);
        float v   = __fdiv_rn(__fmul_rn(27.5f, e), 24000.0f);
        float cut = fminf(fmaxf(v, 0.01f), 0.99f);
        float pole = expf(__fmul_rn(-TWO_PI_F, cut));
        ws[OFF_POLE + j]  = pole;
        ws[OFF_ALPHA + j] = __fsub_rn(1.0f, pole);
        ws[OFF_AT + j] = at;
        ws[OFF_FR + j] = fr;
        ws[OFF_WC + j] = fminf(fmaxf(wfac[j], 0.0f), 2.0f);
        ((unsigned int*)ws)[OFF_PEAK + j] = 0u;   // re-init every call (determinism)
    }
}

// ---------------- kernel 2: harmonic sum via rotation recurrence -------------------
// thread = (b, k-quarter, 8-sample chunk); LDS-reduce the 4 k-quarters.
#define SPT_H 8
#define TBLK  512                      // 64 lanes * 8 samples
#define RROW  528                      // 512 + swizzle pad (SW(511)=526)

__global__ void kharm(const float* __restrict__ prm,
                      float* __restrict__ harm,
                      unsigned int* __restrict__ peak) {
    __shared__ float red[4][RROW];
    __shared__ float mxs[4];
    const int tid  = threadIdx.x;
    const int lane = tid & 63;
    const int kq   = __builtin_amdgcn_readfirstlane(tid >> 6);  // wave-uniform
    const int b    = blockIdx.y;
    const int t0b  = blockIdx.x * TBLK;
    const int t0   = t0b + lane * SPT_H;

    const float fn0 = (float)t0;
    const float tt0 = __fdiv_rn(fn0, 48000.0f);   // bit-exact fl(t0/48000)

    float acc[SPT_H];
#pragma unroll
    for (int j = 0; j < SPT_H; ++j) acc[j] = 0.0f;

    const float* Pb = prm + OFF_PK + (((b << 6) + (kq << 4)) * PK_STRIDE);

#pragma unroll 2
    for (int kk = 0; kk < 16; ++kk) {
        const float* P = Pb + kk * PK_STRIDE;
        float w  = P[0], wb2 = P[1], pm = P[2], pb = P[3];
        float c1 = P[4], c2 = P[5], A1 = P[6], A2 = P[7], bdk = P[8];
        float cd = P[9], sd = P[10], cbd = P[11], sbd = P[12];
        float d1 = P[13], d2 = P[14];

        // exact refresh at t0: reference's own f32 argument bits
        float am = __fadd_rn(__fmul_rn(w,   tt0), pm);
        float ab = __fadd_rn(__fmul_rn(wb2, tt0), pb);
        float rm = reduce_rev(am);
        float rb = reduce_rev(ab);
        float cm = __builtin_amdgcn_cosf(rm), sm = __builtin_amdgcn_sinf(rm);
        float cb = __builtin_amdgcn_cosf(rb), sb = __builtin_amdgcn_sinf(rb);
        float e1 = __builtin_amdgcn_exp2f(__fmul_rn(fn0, c1));
        float e2 = __builtin_amdgcn_exp2f(__fmul_rn(fn0, c2));

#pragma unroll
        for (int j = 0; j < SPT_H; ++j) {
            float env = fmaf(A1, e1, __fmul_rn(A2, e2));
            float osc = fmaf(bdk, cb, cm);
            acc[j] = fmaf(env, osc, acc[j]);
            if (j < SPT_H - 1) {
                float cm2 = fmaf(cm, cd, -__fmul_rn(sm, sd));
                float sm2 = fmaf(sm, cd,  __fmul_rn(cm, sd));
                cm = cm2; sm = sm2;
                float cb2 = fmaf(cb, cbd, -__fmul_rn(sb, sbd));
                float sb2 = fmaf(sb, cbd,  __fmul_rn(cb, sbd));
                cb = cb2; sb = sb2;
                e1 = __fmul_rn(e1, d1);
                e2 = __fmul_rn(e2, d2);
            }
        }
    }

    // write partials (swizzled: 2-way max on banks)
#pragma unroll
    for (int j = 0; j < SPT_H; ++j) {
        int c = lane * SPT_H + j;
        red[kq][c + (c >> 5)] = acc[j];
    }
    __syncthreads();

    // sum the 4 k-quarters; each thread finalizes 2 consecutive samples
    int c0 = tid * 2;
    int c1i = c0 + 1;
    float s0 = 0.0f, s1 = 0.0f;
#pragma unroll
    for (int q = 0; q < 4; ++q) {
        s0 = __fadd_rn(s0, red[q][c0  + (c0  >> 5)]);
        s1 = __fadd_rn(s1, red[q][c1i + (c1i >> 5)]);
    }
    int tg = t0b + c0;
    float m = 0.0f;
    if (tg < T_TOT) {
        *(float2*)(harm + b * T_TOT + tg) = make_float2(s0, s1);
        m = fmaxf(fabsf(s0), fabsf(s1));
    }
#pragma unroll
    for (int off = 32; off > 0; off >>= 1)
        m = fmaxf(m, __shfl_xor(m, off));
    if (lane == 0) mxs[tid >> 6] = m;
    __syncthreads();
    if (tid == 0) {
        float mm = fmaxf(fmaxf(mxs[0], mxs[1]), fmaxf(mxs[2], mxs[3]));
        atomicMax(&peak[b], __float_as_uint(mm));
    }
}

// ---------------- kernel 3: white-noise gen + windowed IIR + epilogue --------------
#define SPT   4
#define CHUNK 1024                       // 256 threads * SPT
#define WIN   (CHUNK + WF - 1)           // 1151
#define WPAD  (WIN + ((WIN + 31) >> 5))  // +idx/32 swizzle pad

__global__ void kfinal(const float* __restrict__ ws, float* __restrict__ out) {
    __shared__ __align__(16) float s[WPAD];
    __shared__ __align__(16) float ptab[WF];
    const int b   = blockIdx.y;
    const int t0  = blockIdx.x * CHUNK;
    const int tid = threadIdx.x;

    const float alpha = ws[OFF_ALPHA + b];
    const float pole  = ws[OFF_POLE + b];
    const float at    = ws[OFF_AT + b];
    const float fr    = ws[OFF_FR + b];
    const float wcf   = ws[OFF_WC + b];
    const float peak  = fmaxf(__uint_as_float(((const unsigned int*)ws)[OFF_PEAK + b]), 1e-6f);
    const float cpk   = __fdiv_rn(0.9f, peak);

    uint32_t k2a, k2b;
    tf2x32(0u, 42u, 0u, 2u, k2a, k2b);   // pk[2]

    // stage aw window [t0-127, t0+CHUNK) into swizzled LDS (generated, not loaded)
    for (int idx = tid; idx < WIN; idx += 256) {
        int j = t0 - (WF - 1) + idx;
        float v = 0.0f;
        if (j >= 0 && j < T_TOT) {
            uint32_t o0, o1;
            tf2x32(k2a, k2b, 0u, (uint32_t)(b * T_TOT + j), o0, o1);
            v = __fmul_rn(alpha, normal_from_bits(o0 ^ o1));
        }
        s[idx + (idx >> 5)] = v;
    }
    if (tid < WF) ptab[tid] = exp2f((float)tid * log2f(pole));   // pole^tid
    __syncthreads();

    int t = t0 + tid * SPT;
    if (t >= N_SAMP) return;
    const float p128 = __fmul_rn(ptab[WF - 1], pole);   // pole^WF
    const int base = tid * SPT + (WF - 1);              // s-index of aw[t]

    // filt[t] = sum_{i<WF} pole^i * aw[t-i]
    float f0 = 0.f, f1 = 0.f, f2 = 0.f, f3 = 0.f;
#pragma unroll
    for (int i = 0; i < WF; i += 4) {
        float4 pv = *(const float4*)&ptab[i];
        int a0 = base - i, a1i = a0 - 1, a2i = a0 - 2, a3i = a0 - 3;
        f0 = fmaf(pv.x, s[a0  + (a0  >> 5)], f0);
        f1 = fmaf(pv.y, s[a1i + (a1i >> 5)], f1);
        f2 = fmaf(pv.z, s[a2i + (a2i >> 5)], f2);
        f3 = fmaf(pv.w, s[a3i + (a3i >> 5)], f3);
    }
    float filt = __fadd_rn(__fadd_rn(f0, f2), __fadd_rn(f1, f3));

    const float* harm = ws + OFF_HARM + b * T_TOT;
    float* outL = out + (b * 2 + 0) * N_SAMP;
    float* outR = out + (b * 2 + 1) * N_SAMP;

#pragma unroll
    for (int jj = 0; jj < SPT; ++jj) {
        int tj = t + jj;
        if (tj >= N_SAMP) break;
        if (jj > 0) {
            // filt[t+1] = pole*filt[t] + aw[t+1] - pole^WF * aw[t+1-WF]  (exact identity)
            int bn = base + jj;
            int bo = bn - WF;
            filt = fmaf(pole, filt, s[bn + (bn >> 5)]);
            filt = fmaf(-p128, s[bo + (bo >> 5)], filt);
        }
        float fnf = (float)tj;
        float tt  = __fdiv_rn(fnf, 48000.0f);
        float hn  = __fmul_rn(harm[tj], cpk);
        float ne  = __fmul_rn(__expf(__fdiv_rn(-tt, at)), fr);
        float ns  = __fmul_rn(filt, ne);
        float mono = __fadd_rn(hn, ns);
        float side = __fmul_rn(__fmul_rn(mono, wcf), 0.3f);
        outL[tj] = fminf(fmaxf(__fadd_rn(mono, side), -1.0f), 1.0f);
        outR[tj] = fminf(fmaxf(__fsub_rn(mono, side), -1.0f), 1.0f);
    }
}

extern "C" void kernel_launch(void* const* d_in, const int* in_sizes, int n_in,
                              void* d_out, int out_size, void* d_ws, size_t ws_size,
                              hipStream_t stream) {
    (void)in_sizes; (void)n_in; (void)out_size; (void)ws_size;
    const float* B_inh   = (const float*)d_in[0];
    const float* f0_off  = (const float*)d_in[1];
    const float* A0      = (const float*)d_in[2];
    const float* tau1    = (const float*)d_in[3];
    const float* tau2    = (const float*)d_in[4];
    const float* a1      = (const float*)d_in[5];
    const float* beat_hz = (const float*)d_in[6];
    const float* beat_dp = (const float*)d_in[7];
    const float* noise   = (const float*)d_in[8];
    const float* f0      = (const float*)d_in[9];
    const float* wfac    = (const float*)d_in[10];
    float* out = (float*)d_out;
    float* ws  = (float*)d_ws;

    kprep<<<dim3(1), dim3(256), 0, stream>>>(B_inh, f0_off, beat_hz, noise, f0, wfac,
                                             A0, tau1, tau2, a1, beat_dp, ws);

    dim3 gh((T_TOT + TBLK - 1) / TBLK, B_BATCH);
    kharm<<<gh, dim3(256), 0, stream>>>(ws, ws + OFF_HARM,
                                        (unsigned int*)ws + OFF_PEAK);

    dim3 gf((N_SAMP + CHUNK - 1) / CHUNK, B_BATCH);
    kfinal<<<gf, dim3(256), 0, stream>>>(ws, out);
}

// Round 6
// 34.220 us; speedup vs baseline: 3.8227x; 1.1167x over previous
//
#include <hip/hip_runtime.h>
#include <stdint.h>
#include <math.h>

#pragma clang fp contract(off)

#define B_BATCH 4
#define K_HARM  64
#define T_TOT   144000   // ceil(3*48000/240)*240 == 3*48000
#define N_SAMP  144000
#define WF      128      // pole<=0.93937 -> pole^128 ~ 3e-4; *noise_env(<=0.011) -> <2e-6 abs

// ws layout (float index)
// packed per-(b,k) params, stride 16 floats (64B):
//   0:w  1:wb  2:phim  3:phib  4:c1'  5:c2'  6:A1  7:A2  8:bd
//   9:cdm 10:sdm 11:cdb 12:sdb 13:d1 14:d2   (15 pad)
#define OFF_PK    0
#define PK_STRIDE 16
#define OFF_POLE  4096
#define OFF_ALPHA 4100
#define OFF_AT    4104
#define OFF_FR    4108
#define OFF_WC    4112
#define OFF_PEAK  4116   // 4 x uint32 (atomicMax on abs-float bits)
#define OFF_HARM  4128   // harmonic, B*T floats
// total floats: 4128 + 576000 = 580,128 (~2.32 MB of d_ws)

static constexpr float  TWO_PI_F = 6.28318530717958647692f; // f32 0x40C90FDB
static constexpr double INV2PI_D = 0.15915494309189535;
static constexpr float  C_HI = (float)INV2PI_D;
static constexpr float  C_LO = (float)(INV2PI_D - (double)((float)INV2PI_D));
static constexpr float  LOG2E_F = 1.44269504088896340736f;
static constexpr float  LN2_F   = 0.69314718055994530942f;

__device__ __forceinline__ uint32_t rotl32(uint32_t x, uint32_t n) {
    return (x << n) | (x >> (32u - n));
}

// threefry-2x32, 20 rounds, exactly as jax._src.prng.threefry2x32
__device__ __forceinline__ void tf2x32(uint32_t k0, uint32_t k1, uint32_t x0, uint32_t x1,
                                       uint32_t& o0, uint32_t& o1) {
    const uint32_t ks2 = k0 ^ k1 ^ 0x1BD11BDAu;
    x0 += k0; x1 += k1;
#define TF_RND(r) { x0 += x1; x1 = rotl32(x1, (r)); x1 ^= x0; }
    TF_RND(13) TF_RND(15) TF_RND(26) TF_RND(6)
    x0 += k1;  x1 += ks2 + 1u;
    TF_RND(17) TF_RND(29) TF_RND(16) TF_RND(24)
    x0 += ks2; x1 += k0 + 2u;
    TF_RND(13) TF_RND(15) TF_RND(26) TF_RND(6)
    x0 += k0;  x1 += k1 + 3u;
    TF_RND(17) TF_RND(29) TF_RND(16) TF_RND(24)
    x0 += k1;  x1 += ks2 + 4u;
    TF_RND(13) TF_RND(15) TF_RND(26) TF_RND(6)
    x0 += ks2; x1 += k0 + 5u;
#undef TF_RND
    o0 = x0; o1 = x1;
}

// pk = jax.random.split(jax.random.key(42), 3); partitionable scheme (validated r1)
__device__ __forceinline__ void get_keys(uint32_t pk[3][2]) {
    tf2x32(0u, 42u, 0u, 0u, pk[0][0], pk[0][1]);
    tf2x32(0u, 42u, 0u, 1u, pk[1][0], pk[1][1]);
    tf2x32(0u, 42u, 0u, 2u, pk[2][0], pk[2][1]);
}

__device__ __forceinline__ uint32_t bits_for(const uint32_t key[2], uint32_t idx) {
    uint32_t o0, o1;
    tf2x32(key[0], key[1], 0u, idx, o0, o1);
    return o0 ^ o1;
}

__device__ __forceinline__ float u01_from_bits(uint32_t bits) {
    return __fsub_rn(__uint_as_float((bits >> 9) | 0x3f800000u), 1.0f);
}

// XLA ErfInv32 (Giles) polynomial; log1p(-x^2) via HW v_log (noise path:
// rel-err budget ~1e-4, this delivers ~1e-6)
__device__ __forceinline__ float erfinv_fast(float x) {
    float v = fmaf(-x, x, 1.0f);                       // 1 - x^2
    float w = __fmul_rn(-LN2_F, __builtin_amdgcn_logf(v));  // -ln(1-x^2)
    float p;
    if (w < 5.0f) {
        w = __fsub_rn(w, 2.5f);
        p = 2.81022636e-08f;
        p = fmaf(p, w, 3.43273939e-07f);
        p = fmaf(p, w, -3.5233877e-06f);
        p = fmaf(p, w, -4.39150654e-06f);
        p = fmaf(p, w, 0.00021858087f);
        p = fmaf(p, w, -0.00125372503f);
        p = fmaf(p, w, -0.00417768164f);
        p = fmaf(p, w, 0.246640727f);
        p = fmaf(p, w, 1.50140941f);
    } else {
        w = __fsub_rn(sqrtf(w), 3.0f);
        p = -0.000200214257f;
        p = fmaf(p, w, 0.000100950558f);
        p = fmaf(p, w, 0.00134934322f);
        p = fmaf(p, w, -0.00367342844f);
        p = fmaf(p, w, 0.00573950773f);
        p = fmaf(p, w, -0.0076224613f);
        p = fmaf(p, w, 0.00943887047f);
        p = fmaf(p, w, 1.00167406f);
        p = fmaf(p, w, 2.83297682f);
    }
    return __fmul_rn(p, x);
}

__device__ __forceinline__ float normal_from_bits(uint32_t bits) {
    const float LO = __uint_as_float(0xBF7FFFFFu); // nextafterf(-1, 0)
    float f = u01_from_bits(bits);
    float u = __fadd_rn(__fmul_rn(f, 2.0f), LO);
    u = fmaxf(u, LO);
    const float SQRT2_F = 1.41421356237309504880f;
    return __fmul_rn(SQRT2_F, erfinv_fast(u));
}

// f32 Cody-Waite: radians -> reduced revolutions in [-0.5, 0.5]
__device__ __forceinline__ float reduce_rev(float arg) {
    float p = __fmul_rn(arg, C_HI);
    float e = fmaf(arg, C_HI, -p);            // exact tail of arg*C_HI
    float n = rintf(p);                       // exact (p < 2^18 < 2^24)
    float r = __fadd_rn(__fsub_rn(p, n), e);  // p-n exact by Sterbenz
    return fmaf(arg, C_LO, r);
}

// ---------------- kernel 1: per-(b,k) params, phases, per-b scalars ----------------
__global__ void kprep(const float* __restrict__ B_inh, const float* __restrict__ f0_off,
                      const float* __restrict__ beat_hz, const float* __restrict__ noise,
                      const float* __restrict__ f0, const float* __restrict__ wfac,
                      const float* __restrict__ A0, const float* __restrict__ tau1,
                      const float* __restrict__ tau2, const float* __restrict__ a1,
                      const float* __restrict__ bd,
                      float* __restrict__ ws) {
    int j = threadIdx.x;              // 0..255 = b*64 + k
    uint32_t pk[3][2];
    get_keys(pk);

    float phim = __fmul_rn(u01_from_bits(bits_for(pk[0], (uint32_t)j)), TWO_PI_F);
    float phib = __fmul_rn(u01_from_bits(bits_for(pk[1], (uint32_t)j)), TWO_PI_F);

    int b = j >> 6;
    int k = (j & 63) + 1;
    float x   = __fdiv_rn(f0_off[b], 1200.0f);
    float s   = (float)exp2((double)x);
    float f0a = __fmul_rn(f0[b], s);
    float sq  = sqrtf(__fadd_rn(1.0f, __fmul_rn(B_inh[b], (float)(k * k))));
    float fk  = __fmul_rn(__fmul_rn(f0a, (float)k), sq);
    float fkb = __fadd_rn(fk, beat_hz[j]);

    float w_  = __fmul_rn(TWO_PI_F, fk);
    float wb_ = __fmul_rn(TWO_PI_F, fkb);
    float c1  = __fdiv_rn(-LOG2E_F, __fmul_rn(48000.0f, tau1[j]));
    float c2  = __fdiv_rn(-LOG2E_F, __fmul_rn(48000.0f, tau2[j]));

    float* P = ws + OFF_PK + j * PK_STRIDE;
    P[0] = w_;
    P[1] = wb_;
    P[2] = phim;
    P[3] = phib;
    P[4] = c1;
    P[5] = c2;
    float a1v = a1[j];
    P[6] = __fmul_rn(A0[j], a1v);
    P[7] = __fmul_rn(A0[j], __fsub_rn(1.0f, a1v));
    P[8] = bd[j];
    // step constants for Chebyshev / decay recurrences (f64 once)
    double dth  = (double)w_  / 48000.0;
    double dthb = (double)wb_ / 48000.0;
    P[9]  = (float)cos(dth);
    P[10] = (float)sin(dth);
    P[11] = (float)cos(dthb);
    P[12] = (float)sin(dthb);
    P[13] = (float)exp2((double)c1);
    P[14] = (float)exp2((double)c2);

    if (j < B_BATCH) {
        float at  = fmaxf(noise[j * 4 + 0], 0.002f);
        float fr  = noise[j * 4 + 1];
        float cen = noise[j * 4 + 2];
        float lr  = (float)log2(24000.0 / 27.5);
        float y   = __fmul_rn(cen, lr);
        float e   = (float)exp2((double)y);
        float v   = __fdiv_rn(__fmul_rn(27.5f, e), 24000.0f);
        float cut = fminf(fmaxf(v, 0.01f), 0.99f);
        float pole = expf(__fmul_rn(-TWO_PI_F, cut));
        ws[OFF_POLE + j]  = pole;
        ws[OFF_ALPHA + j] = __fsub_rn(1.0f, pole);
        ws[OFF_AT + j] = at;
        ws[OFF_FR + j] = fr;
        ws[OFF_WC + j] = fminf(fmaxf(wfac[j], 0.0f), 2.0f);
        ((unsigned int*)ws)[OFF_PEAK + j] = 0u;   // re-init every call (determinism)
    }
}

// ---------------- kernel 2: harmonic sum via Chebyshev 2-term recurrence -----------
// thread = (b, k-quarter, 8-sample chunk); LDS-reduce the 4 k-quarters.
// x[n+1] = 2cos(D)*x[n] - x[n-1] tracks cos(theta0 + nD): 1 FMA per oscillator.
#define SPT_H 8
#define TBLK  512                      // 64 lanes * 8 samples
#define RROW  528                      // 512 + swizzle pad

__global__ void kharm(const float* __restrict__ prm,
                      float* __restrict__ harm,
                      unsigned int* __restrict__ peak) {
    __shared__ float red[4][RROW];
    __shared__ float mxs[4];
    const int tid  = threadIdx.x;
    const int lane = tid & 63;
    const int kq   = __builtin_amdgcn_readfirstlane(tid >> 6);  // wave-uniform
    const int b    = blockIdx.y;
    const int t0b  = blockIdx.x * TBLK;
    const int t0   = t0b + lane * SPT_H;

    const float fn0 = (float)t0;
    const float tt0 = __fdiv_rn(fn0, 48000.0f);   // bit-exact fl(t0/48000)

    float acc[SPT_H];
#pragma unroll
    for (int j = 0; j < SPT_H; ++j) acc[j] = 0.0f;

    const float* Pb = prm + OFF_PK + (((b << 6) + (kq << 4)) * PK_STRIDE);

#pragma unroll 2
    for (int kk = 0; kk < 16; ++kk) {
        const float* P = Pb + kk * PK_STRIDE;
        float w  = P[0], wb2 = P[1], pm = P[2], pb = P[3];
        float c1 = P[4], c2 = P[5], A1 = P[6], A2 = P[7], bdk = P[8];
        float cdm = P[9], sdm = P[10], cdb = P[11], sdb = P[12];
        float d1 = P[13], d2 = P[14];

        // exact refresh at t0: reference's own f32 argument bits
        float am = __fadd_rn(__fmul_rn(w,   tt0), pm);
        float ab = __fadd_rn(__fmul_rn(wb2, tt0), pb);
        float rm = reduce_rev(am);
        float rb = reduce_rev(ab);
        float cm = __builtin_amdgcn_cosf(rm), sm = __builtin_amdgcn_sinf(rm);
        float cb = __builtin_amdgcn_cosf(rb), sb = __builtin_amdgcn_sinf(rb);

        // Chebyshev states (bd folded into beat oscillator; A folded into env)
        float xm  = cm;                                      // cos(th0)
        float xpm = fmaf(sm, sdm, __fmul_rn(cm, cdm));       // cos(th0 - Dm)
        float xb  = __fmul_rn(bdk, cb);
        float xpb = __fmul_rn(bdk, fmaf(sb, sdb, __fmul_rn(cb, cdb)));
        float km  = __fadd_rn(cdm, cdm);                     // 2cos(Dm)
        float kb2 = __fadd_rn(cdb, cdb);
        float e1  = __fmul_rn(A1, __builtin_amdgcn_exp2f(__fmul_rn(fn0, c1)));
        float e2  = __fmul_rn(A2, __builtin_amdgcn_exp2f(__fmul_rn(fn0, c2)));

#pragma unroll
        for (int j = 0; j < SPT_H; ++j) {
            float env = __fadd_rn(e1, e2);
            float osc = __fadd_rn(xm, xb);
            acc[j] = fmaf(env, osc, acc[j]);
            if (j < SPT_H - 1) {
                float xn  = fmaf(km,  xm, -xpm); xpm = xm; xm = xn;
                float xbn = fmaf(kb2, xb, -xpb); xpb = xb; xb = xbn;
                e1 = __fmul_rn(e1, d1);
                e2 = __fmul_rn(e2, d2);
            }
        }
    }

    // write partials (swizzled: 2-way max on banks)
#pragma unroll
    for (int j = 0; j < SPT_H; ++j) {
        int c = lane * SPT_H + j;
        red[kq][c + (c >> 5)] = acc[j];
    }
    __syncthreads();

    // sum the 4 k-quarters; each thread finalizes 2 consecutive samples
    int c0 = tid * 2;
    int c1i = c0 + 1;
    float s0 = 0.0f, s1 = 0.0f;
#pragma unroll
    for (int q = 0; q < 4; ++q) {
        s0 = __fadd_rn(s0, red[q][c0  + (c0  >> 5)]);
        s1 = __fadd_rn(s1, red[q][c1i + (c1i >> 5)]);
    }
    int tg = t0b + c0;
    float m = 0.0f;
    if (tg < T_TOT) {
        *(float2*)(harm + b * T_TOT + tg) = make_float2(s0, s1);
        m = fmaxf(fabsf(s0), fabsf(s1));
    }
#pragma unroll
    for (int off = 32; off > 0; off >>= 1)
        m = fmaxf(m, __shfl_xor(m, off));
    if (lane == 0) mxs[tid >> 6] = m;
    __syncthreads();
    if (tid == 0) {
        float mm = fmaxf(fmaxf(mxs[0], mxs[1]), fmaxf(mxs[2], mxs[3]));
        atomicMax(&peak[b], __float_as_uint(mm));
    }
}

// ---------------- kernel 3: white-noise gen + windowed IIR + epilogue --------------
#define SPT   4
#define CHUNK 1024                       // 256 threads * SPT
#define WIN   (CHUNK + WF - 1)           // 1151

__global__ void kfinal(const float* __restrict__ ws, float* __restrict__ out) {
    __shared__ __align__(16) float s[WIN + 1];   // unswizzled (16B-aligned quads)
    __shared__ __align__(16) float ptab[WF];
    const int b   = blockIdx.y;
    const int t0  = blockIdx.x * CHUNK;
    const int tid = threadIdx.x;

    const float alpha = ws[OFF_ALPHA + b];
    const float pole  = ws[OFF_POLE + b];
    const float at    = ws[OFF_AT + b];
    const float fr    = ws[OFF_FR + b];
    const float wcf   = ws[OFF_WC + b];
    const float peak  = fmaxf(__uint_as_float(((const unsigned int*)ws)[OFF_PEAK + b]), 1e-6f);
    const float cpk   = __fdiv_rn(0.9f, peak);

    uint32_t k2a, k2b;
    tf2x32(0u, 42u, 0u, 2u, k2a, k2b);   // pk[2]

    // stage aw window [t0-127, t0+CHUNK) into LDS (generated, not loaded)
    for (int idx = tid; idx < WIN; idx += 256) {
        int j = t0 - (WF - 1) + idx;
        float v = 0.0f;
        if (j >= 0 && j < T_TOT) {
            uint32_t o0, o1;
            tf2x32(k2a, k2b, 0u, (uint32_t)(b * T_TOT + j), o0, o1);
            v = __fmul_rn(alpha, normal_from_bits(o0 ^ o1));
        }
        s[idx] = v;
    }
    if (tid < WF) ptab[tid] = exp2f((float)tid * log2f(pole));   // pole^tid
    __syncthreads();

    const int t = t0 + tid * SPT;
    if (t >= N_SAMP) return;                 // N_SAMP%4==0: all-or-none per thread
    const float p128 = __fmul_rn(ptab[WF - 1], pole);   // pole^WF
    const int base = tid * SPT + (WF - 1);   // s-index of aw[t]; base%4==3

    // filt[t] = sum_{i<WF} ptab[i] * s[base-i] -- float4 both sides
    float f0 = 0.f, f1 = 0.f, f2 = 0.f, f3 = 0.f;
#pragma unroll
    for (int m4 = 0; m4 < WF / 4; ++m4) {
        float4 p4 = *(const float4*)&ptab[m4 * 4];
        float4 s4 = *(const float4*)&s[base - m4 * 4 - 3];   // 16B-aligned
        f0 = fmaf(p4.x, s4.w, f0);
        f1 = fmaf(p4.y, s4.z, f1);
        f2 = fmaf(p4.z, s4.y, f2);
        f3 = fmaf(p4.w, s4.x, f3);
    }
    float filt = __fadd_rn(__fadd_rn(f0, f2), __fadd_rn(f1, f3));

    const float4 h4 = *(const float4*)(ws + OFF_HARM + b * T_TOT + t);
    float* outL = out + (b * 2 + 0) * N_SAMP;
    float* outR = out + (b * 2 + 1) * N_SAMP;

    // noise envelope: exact at jj=0, multiplicative decay after (rel err ~1e-7/step)
    float tt  = __fdiv_rn((float)t, 48000.0f);
    float ne  = __fmul_rn(__expf(__fdiv_rn(-tt, at)), fr);
    const float ned = __expf(__fdiv_rn(-1.0f, __fmul_rn(48000.0f, at)));

    float4 L, R;
    const float hv[4] = {h4.x, h4.y, h4.z, h4.w};
    float lv[4], rv[4];
#pragma unroll
    for (int jj = 0; jj < SPT; ++jj) {
        if (jj > 0) {
            // filt[t+1] = pole*filt[t] + aw[t+1] - pole^WF * aw[t+1-WF]
            filt = fmaf(pole, filt, s[base + jj]);
            filt = fmaf(-p128, s[base + jj - WF], filt);
            ne   = __fmul_rn(ne, ned);
        }
        float hn   = __fmul_rn(hv[jj], cpk);
        float ns   = __fmul_rn(filt, ne);
        float mono = __fadd_rn(hn, ns);
        float side = __fmul_rn(__fmul_rn(mono, wcf), 0.3f);
        lv[jj] = fminf(fmaxf(__fadd_rn(mono, side), -1.0f), 1.0f);
        rv[jj] = fminf(fmaxf(__fsub_rn(mono, side), -1.0f), 1.0f);
    }
    L = make_float4(lv[0], lv[1], lv[2], lv[3]);
    R = make_float4(rv[0], rv[1], rv[2], rv[3]);
    *(float4*)&outL[t] = L;
    *(float4*)&outR[t] = R;
}

extern "C" void kernel_launch(void* const* d_in, const int* in_sizes, int n_in,
                              void* d_out, int out_size, void* d_ws, size_t ws_size,
                              hipStream_t stream) {
    (void)in_sizes; (void)n_in; (void)out_size; (void)ws_size;
    const float* B_inh   = (const float*)d_in[0];
    const float* f0_off  = (const float*)d_in[1];
    const float* A0      = (const float*)d_in[2];
    const float* tau1    = (const float*)d_in[3];
    const float* tau2    = (const float*)d_in[4];
    const float* a1      = (const float*)d_in[5];
    const float* beat_hz = (const float*)d_in[6];
    const float* beat_dp = (const float*)d_in[7];
    const float* noise   = (const float*)d_in[8];
    const float* f0      = (const float*)d_in[9];
    const float* wfac    = (const float*)d_in[10];
    float* out = (float*)d_out;
    float* ws  = (float*)d_ws;

    kprep<<<dim3(1), dim3(256), 0, stream>>>(B_inh, f0_off, beat_hz, noise, f0, wfac,
                                             A0, tau1, tau2, a1, beat_dp, ws);

    dim3 gh((T_TOT + TBLK - 1) / TBLK, B_BATCH);
    kharm<<<gh, dim3(256), 0, stream>>>(ws, ws + OFF_HARM,
                                        (unsigned int*)ws + OFF_PEAK);

    dim3 gf((N_SAMP + CHUNK - 1) / CHUNK, B_BATCH);
    kfinal<<<gf, dim3(256), 0, stream>>>(ws, out);
}

// Round 7
// 28.728 us; speedup vs baseline: 4.5535x; 1.1912x over previous
//
#include <hip/hip_runtime.h>
#include <stdint.h>
#include <math.h>

#pragma clang fp contract(off)

#define B_BATCH 4
#define K_HARM  64
#define T_TOT   144000   // ceil(3*48000/240)*240 == 3*48000
#define N_SAMP  144000
#define WF      128      // pole<=0.93937 -> pole^128 ~ 3e-4; *noise_env(<=0.011) -> <2e-6 abs

// ws layout (float index)
// packed per-(b,k) params, stride 16 floats (64B):
//   0:w  1:wb  2:phim  3:phib  4:c1'  5:c2'  6:A1  7:A2  8:bd
//   9:cdm 10:sdm 11:cdb 12:sdb 13:d1 14:d2   (15 pad)
#define OFF_PK    0
#define PK_STRIDE 16
#define OFF_POLE  4096
#define OFF_ALPHA 4100
#define OFF_AT    4104
#define OFF_FR    4108
#define OFF_WC    4112
#define OFF_PEAK  4116   // 4 x uint32 (atomicMax on abs-float bits)
#define OFF_HARM  4128   // harmonic, B*T floats
// total floats: 4128 + 576000 = 580,128 (~2.32 MB of d_ws)

static constexpr float  TWO_PI_F = 6.28318530717958647692f; // f32 0x40C90FDB
static constexpr double INV2PI_D = 0.15915494309189535;
static constexpr float  C_HI = (float)INV2PI_D;
static constexpr float  C_LO = (float)(INV2PI_D - (double)((float)INV2PI_D));
static constexpr float  LOG2E_F = 1.44269504088896340736f;
static constexpr float  LN2_F   = 0.69314718055994530942f;

__device__ __forceinline__ uint32_t rotl32(uint32_t x, uint32_t n) {
    return (x << n) | (x >> (32u - n));
}

// threefry-2x32, 20 rounds, exactly as jax._src.prng.threefry2x32
__device__ __forceinline__ void tf2x32(uint32_t k0, uint32_t k1, uint32_t x0, uint32_t x1,
                                       uint32_t& o0, uint32_t& o1) {
    const uint32_t ks2 = k0 ^ k1 ^ 0x1BD11BDAu;
    x0 += k0; x1 += k1;
#define TF_RND(r) { x0 += x1; x1 = rotl32(x1, (r)); x1 ^= x0; }
    TF_RND(13) TF_RND(15) TF_RND(26) TF_RND(6)
    x0 += k1;  x1 += ks2 + 1u;
    TF_RND(17) TF_RND(29) TF_RND(16) TF_RND(24)
    x0 += ks2; x1 += k0 + 2u;
    TF_RND(13) TF_RND(15) TF_RND(26) TF_RND(6)
    x0 += k0;  x1 += k1 + 3u;
    TF_RND(17) TF_RND(29) TF_RND(16) TF_RND(24)
    x0 += k1;  x1 += ks2 + 4u;
    TF_RND(13) TF_RND(15) TF_RND(26) TF_RND(6)
    x0 += ks2; x1 += k0 + 5u;
#undef TF_RND
    o0 = x0; o1 = x1;
}

// pk = jax.random.split(jax.random.key(42), 3); partitionable scheme (validated r1)
__device__ __forceinline__ void get_keys(uint32_t pk[3][2]) {
    tf2x32(0u, 42u, 0u, 0u, pk[0][0], pk[0][1]);
    tf2x32(0u, 42u, 0u, 1u, pk[1][0], pk[1][1]);
    tf2x32(0u, 42u, 0u, 2u, pk[2][0], pk[2][1]);
}

__device__ __forceinline__ uint32_t bits_for(const uint32_t key[2], uint32_t idx) {
    uint32_t o0, o1;
    tf2x32(key[0], key[1], 0u, idx, o0, o1);
    return o0 ^ o1;
}

__device__ __forceinline__ float u01_from_bits(uint32_t bits) {
    return __fsub_rn(__uint_as_float((bits >> 9) | 0x3f800000u), 1.0f);
}

// XLA ErfInv32 (Giles) polynomial; log1p(-x^2) via HW v_log (noise path:
// rel-err budget ~1e-4, this delivers ~1e-6)
__device__ __forceinline__ float erfinv_fast(float x) {
    float v = fmaf(-x, x, 1.0f);                       // 1 - x^2
    float w = __fmul_rn(-LN2_F, __builtin_amdgcn_logf(v));  // -ln(1-x^2)
    float p;
    if (w < 5.0f) {
        w = __fsub_rn(w, 2.5f);
        p = 2.81022636e-08f;
        p = fmaf(p, w, 3.43273939e-07f);
        p = fmaf(p, w, -3.5233877e-06f);
        p = fmaf(p, w, -4.39150654e-06f);
        p = fmaf(p, w, 0.00021858087f);
        p = fmaf(p, w, -0.00125372503f);
        p = fmaf(p, w, -0.00417768164f);
        p = fmaf(p, w, 0.246640727f);
        p = fmaf(p, w, 1.50140941f);
    } else {
        w = __fsub_rn(sqrtf(w), 3.0f);
        p = -0.000200214257f;
        p = fmaf(p, w, 0.000100950558f);
        p = fmaf(p, w, 0.00134934322f);
        p = fmaf(p, w, -0.00367342844f);
        p = fmaf(p, w, 0.00573950773f);
        p = fmaf(p, w, -0.0076224613f);
        p = fmaf(p, w, 0.00943887047f);
        p = fmaf(p, w, 1.00167406f);
        p = fmaf(p, w, 2.83297682f);
    }
    return __fmul_rn(p, x);
}

__device__ __forceinline__ float normal_from_bits(uint32_t bits) {
    const float LO = __uint_as_float(0xBF7FFFFFu); // nextafterf(-1, 0)
    float f = u01_from_bits(bits);
    float u = __fadd_rn(__fmul_rn(f, 2.0f), LO);
    u = fmaxf(u, LO);
    const float SQRT2_F = 1.41421356237309504880f;
    return __fmul_rn(SQRT2_F, erfinv_fast(u));
}

// f32 Cody-Waite: radians -> reduced revolutions in [-0.5, 0.5]
__device__ __forceinline__ float reduce_rev(float arg) {
    float p = __fmul_rn(arg, C_HI);
    float e = fmaf(arg, C_HI, -p);            // exact tail of arg*C_HI
    float n = rintf(p);                       // exact (p < 2^18 < 2^24)
    float r = __fadd_rn(__fsub_rn(p, n), e);  // p-n exact by Sterbenz
    return fmaf(arg, C_LO, r);
}

// ---------------- kernel 1: per-(b,k) params, phases, per-b scalars ----------------
__global__ void kprep(const float* __restrict__ B_inh, const float* __restrict__ f0_off,
                      const float* __restrict__ beat_hz, const float* __restrict__ noise,
                      const float* __restrict__ f0, const float* __restrict__ wfac,
                      const float* __restrict__ A0, const float* __restrict__ tau1,
                      const float* __restrict__ tau2, const float* __restrict__ a1,
                      const float* __restrict__ bd,
                      float* __restrict__ ws) {
    int j = threadIdx.x;              // 0..255 = b*64 + k
    uint32_t pk[3][2];
    get_keys(pk);

    float phim = __fmul_rn(u01_from_bits(bits_for(pk[0], (uint32_t)j)), TWO_PI_F);
    float phib = __fmul_rn(u01_from_bits(bits_for(pk[1], (uint32_t)j)), TWO_PI_F);

    int b = j >> 6;
    int k = (j & 63) + 1;
    float x   = __fdiv_rn(f0_off[b], 1200.0f);
    float s   = (float)exp2((double)x);     // reference-bit-exact path: keep f64
    float f0a = __fmul_rn(f0[b], s);
    float sq  = sqrtf(__fadd_rn(1.0f, __fmul_rn(B_inh[b], (float)(k * k))));
    float fk  = __fmul_rn(__fmul_rn(f0a, (float)k), sq);
    float fkb = __fadd_rn(fk, beat_hz[j]);

    float w_  = __fmul_rn(TWO_PI_F, fk);
    float wb_ = __fmul_rn(TWO_PI_F, fkb);
    float c1  = __fdiv_rn(-LOG2E_F, __fmul_rn(48000.0f, tau1[j]));
    float c2  = __fdiv_rn(-LOG2E_F, __fmul_rn(48000.0f, tau2[j]));

    float* P = ws + OFF_PK + j * PK_STRIDE;
    P[0] = w_;
    P[1] = wb_;
    P[2] = phim;
    P[3] = phib;
    P[4] = c1;
    P[5] = c2;
    float a1v = a1[j];
    P[6] = __fmul_rn(A0[j], a1v);
    P[7] = __fmul_rn(A0[j], __fsub_rn(1.0f, a1v));
    P[8] = bd[j];
    // step constants for Chebyshev / decay recurrences: tolerance-level accuracy
    // (phase drift <= ~1e-4 rad over 15 steps) -> HW f32 trans, not f64.
    // angle step in REVOLUTIONS = f/48000 (may exceed 1 -> take fract)
    float revm = __fdiv_rn(fk,  48000.0f); revm = __fsub_rn(revm, floorf(revm));
    float revb = __fdiv_rn(fkb, 48000.0f); revb = __fsub_rn(revb, floorf(revb));
    P[9]  = __builtin_amdgcn_cosf(revm);
    P[10] = __builtin_amdgcn_sinf(revm);
    P[11] = __builtin_amdgcn_cosf(revb);
    P[12] = __builtin_amdgcn_sinf(revb);
    P[13] = __builtin_amdgcn_exp2f(c1);
    P[14] = __builtin_amdgcn_exp2f(c2);

    if (j < B_BATCH) {
        float at  = fmaxf(noise[j * 4 + 0], 0.002f);
        float fr  = noise[j * 4 + 1];
        float cen = noise[j * 4 + 2];
        float lr  = (float)log2(24000.0 / 27.5);
        float y   = __fmul_rn(cen, lr);
        float e   = (float)exp2((double)y);  // reference-bit-exact path: keep f64
        float v   = __fdiv_rn(__fmul_rn(27.5f, e), 24000.0f);
        float cut = fminf(fmaxf(v, 0.01f), 0.99f);
        float pole = expf(__fmul_rn(-TWO_PI_F, cut));
        ws[OFF_POLE + j]  = pole;
        ws[OFF_ALPHA + j] = __fsub_rn(1.0f, pole);
        ws[OFF_AT + j] = at;
        ws[OFF_FR + j] = fr;
        ws[OFF_WC + j] = fminf(fmaxf(wfac[j], 0.0f), 2.0f);
        ((unsigned int*)ws)[OFF_PEAK + j] = 0u;   // re-init every call (determinism)
    }
}

// ---------------- kernel 2: harmonic sum via Chebyshev 2-term recurrence -----------
// 512-thread block = 8 waves; wave = one k-octant (8 k's) x 1024 samples
// (64 lanes x 16 samples). LDS-reduce the 8 octants. Same wave count as r5/r6
// (4512 = 4.4/SIMD) but refresh+load overhead amortized over 16 samples.
#define SPT_H 16
#define TBLK  1024                     // 64 lanes * 16 samples
#define KQ_N  8
#define RROW  1056                     // 1024 + 1024/32 swizzle pad

__global__ void kharm(const float* __restrict__ prm,
                      float* __restrict__ harm,
                      unsigned int* __restrict__ peak) {
    __shared__ float red[KQ_N][RROW];
    __shared__ float mxs[KQ_N];
    const int tid  = threadIdx.x;      // 0..511
    const int lane = tid & 63;
    const int kq   = __builtin_amdgcn_readfirstlane(tid >> 6);  // 0..7, wave-uniform
    const int b    = blockIdx.y;
    const int t0b  = blockIdx.x * TBLK;
    const int t0   = t0b + lane * SPT_H;

    const float fn0 = (float)t0;
    const float tt0 = __fdiv_rn(fn0, 48000.0f);   // bit-exact fl(t0/48000)

    float acc[SPT_H];
#pragma unroll
    for (int j = 0; j < SPT_H; ++j) acc[j] = 0.0f;

    const float* Pb = prm + OFF_PK + (((b << 6) + (kq << 3)) * PK_STRIDE);

#pragma unroll 2
    for (int kk = 0; kk < K_HARM / KQ_N; ++kk) {
        const float* P = Pb + kk * PK_STRIDE;
        float w  = P[0], wb2 = P[1], pm = P[2], pb = P[3];
        float c1 = P[4], c2 = P[5], A1 = P[6], A2 = P[7], bdk = P[8];
        float cdm = P[9], sdm = P[10], cdb = P[11], sdb = P[12];
        float d1 = P[13], d2 = P[14];

        // exact refresh at t0: reference's own f32 argument bits
        float am = __fadd_rn(__fmul_rn(w,   tt0), pm);
        float ab = __fadd_rn(__fmul_rn(wb2, tt0), pb);
        float rm = reduce_rev(am);
        float rb = reduce_rev(ab);
        float cm = __builtin_amdgcn_cosf(rm), sm = __builtin_amdgcn_sinf(rm);
        float cb = __builtin_amdgcn_cosf(rb), sb = __builtin_amdgcn_sinf(rb);

        // Chebyshev states (bd folded into beat oscillator; A folded into env)
        float xm  = cm;                                      // cos(th0)
        float xpm = fmaf(sm, sdm, __fmul_rn(cm, cdm));       // cos(th0 - Dm)
        float xb  = __fmul_rn(bdk, cb);
        float xpb = __fmul_rn(bdk, fmaf(sb, sdb, __fmul_rn(cb, cdb)));
        float km  = __fadd_rn(cdm, cdm);                     // 2cos(Dm)
        float kb2 = __fadd_rn(cdb, cdb);
        float e1  = __fmul_rn(A1, __builtin_amdgcn_exp2f(__fmul_rn(fn0, c1)));
        float e2  = __fmul_rn(A2, __builtin_amdgcn_exp2f(__fmul_rn(fn0, c2)));

#pragma unroll
        for (int j = 0; j < SPT_H; ++j) {
            float env = __fadd_rn(e1, e2);
            float osc = __fadd_rn(xm, xb);
            acc[j] = fmaf(env, osc, acc[j]);
            if (j < SPT_H - 1) {
                float xn  = fmaf(km,  xm, -xpm); xpm = xm; xm = xn;
                float xbn = fmaf(kb2, xb, -xpb); xpb = xb; xb = xbn;
                e1 = __fmul_rn(e1, d1);
                e2 = __fmul_rn(e2, d2);
            }
        }
    }

    // write partials (swizzled: 2-way max on banks)
#pragma unroll
    for (int j = 0; j < SPT_H; ++j) {
        int c = lane * SPT_H + j;
        red[kq][c + (c >> 5)] = acc[j];
    }
    __syncthreads();

    // sum the 8 k-octants; each thread finalizes 2 consecutive samples
    int c0  = tid * 2;
    int c1i = c0 + 1;
    int tg  = t0b + c0;
    float m = 0.0f;
    if (tg < T_TOT) {                  // T_TOT even: pair all-or-none
        float s0 = 0.0f, s1 = 0.0f;
#pragma unroll
        for (int q = 0; q < KQ_N; ++q) {
            s0 = __fadd_rn(s0, red[q][c0  + (c0  >> 5)]);
            s1 = __fadd_rn(s1, red[q][c1i + (c1i >> 5)]);
        }
        *(float2*)(harm + b * T_TOT + tg) = make_float2(s0, s1);
        m = fmaxf(fabsf(s0), fabsf(s1));
    }
#pragma unroll
    for (int off = 32; off > 0; off >>= 1)
        m = fmaxf(m, __shfl_xor(m, off));
    if (lane == 0) mxs[tid >> 6] = m;
    __syncthreads();
    if (tid == 0) {
        float mm = mxs[0];
#pragma unroll
        for (int q = 1; q < KQ_N; ++q) mm = fmaxf(mm, mxs[q]);
        atomicMax(&peak[b], __float_as_uint(mm));
    }
}

// ---------------- kernel 3: white-noise gen + windowed IIR + epilogue --------------
#define SPT   4
#define CHUNK 1024                       // 256 threads * SPT
#define WIN   (CHUNK + WF - 1)           // 1151

__global__ void kfinal(const float* __restrict__ ws, float* __restrict__ out) {
    __shared__ __align__(16) float s[WIN + 1];   // unswizzled (16B-aligned quads)
    __shared__ __align__(16) float ptab[WF];
    const int b   = blockIdx.y;
    const int t0  = blockIdx.x * CHUNK;
    const int tid = threadIdx.x;

    const float alpha = ws[OFF_ALPHA + b];
    const float pole  = ws[OFF_POLE + b];
    const float at    = ws[OFF_AT + b];
    const float fr    = ws[OFF_FR + b];
    const float wcf   = ws[OFF_WC + b];
    const float peak  = fmaxf(__uint_as_float(((const unsigned int*)ws)[OFF_PEAK + b]), 1e-6f);
    const float cpk   = __fdiv_rn(0.9f, peak);

    uint32_t k2a, k2b;
    tf2x32(0u, 42u, 0u, 2u, k2a, k2b);   // pk[2]

    // stage aw window [t0-127, t0+CHUNK) into LDS (generated, not loaded)
    for (int idx = tid; idx < WIN; idx += 256) {
        int j = t0 - (WF - 1) + idx;
        float v = 0.0f;
        if (j >= 0 && j < T_TOT) {
            uint32_t o0, o1;
            tf2x32(k2a, k2b, 0u, (uint32_t)(b * T_TOT + j), o0, o1);
            v = __fmul_rn(alpha, normal_from_bits(o0 ^ o1));
        }
        s[idx] = v;
    }
    if (tid < WF) ptab[tid] = exp2f((float)tid * log2f(pole));   // pole^tid
    __syncthreads();

    const int t = t0 + tid * SPT;
    if (t >= N_SAMP) return;                 // N_SAMP%4==0: all-or-none per thread
    const float p128 = __fmul_rn(ptab[WF - 1], pole);   // pole^WF
    const int base = tid * SPT + (WF - 1);   // s-index of aw[t]; base%4==3

    // filt[t] = sum_{i<WF} ptab[i] * s[base-i] -- float4 both sides
    float f0 = 0.f, f1 = 0.f, f2 = 0.f, f3 = 0.f;
#pragma unroll
    for (int m4 = 0; m4 < WF / 4; ++m4) {
        float4 p4 = *(const float4*)&ptab[m4 * 4];
        float4 s4 = *(const float4*)&s[base - m4 * 4 - 3];   // 16B-aligned
        f0 = fmaf(p4.x, s4.w, f0);
        f1 = fmaf(p4.y, s4.z, f1);
        f2 = fmaf(p4.z, s4.y, f2);
        f3 = fmaf(p4.w, s4.x, f3);
    }
    float filt = __fadd_rn(__fadd_rn(f0, f2), __fadd_rn(f1, f3));

    const float4 h4 = *(const float4*)(ws + OFF_HARM + b * T_TOT + t);
    float* outL = out + (b * 2 + 0) * N_SAMP;
    float* outR = out + (b * 2 + 1) * N_SAMP;

    // noise envelope: exact at jj=0, multiplicative decay after (rel err ~1e-7/step)
    float tt  = __fdiv_rn((float)t, 48000.0f);
    float ne  = __fmul_rn(__expf(__fdiv_rn(-tt, at)), fr);
    const float ned = __expf(__fdiv_rn(-1.0f, __fmul_rn(48000.0f, at)));

    const float hv[4] = {h4.x, h4.y, h4.z, h4.w};
    float lv[4], rv[4];
#pragma unroll
    for (int jj = 0; jj < SPT; ++jj) {
        if (jj > 0) {
            // filt[t+1] = pole*filt[t] + aw[t+1] - pole^WF * aw[t+1-WF]
            filt = fmaf(pole, filt, s[base + jj]);
            filt = fmaf(-p128, s[base + jj - WF], filt);
            ne   = __fmul_rn(ne, ned);
        }
        float hn   = __fmul_rn(hv[jj], cpk);
        float ns   = __fmul_rn(filt, ne);
        float mono = __fadd_rn(hn, ns);
        float side = __fmul_rn(__fmul_rn(mono, wcf), 0.3f);
        lv[jj] = fminf(fmaxf(__fadd_rn(mono, side), -1.0f), 1.0f);
        rv[jj] = fminf(fmaxf(__fsub_rn(mono, side), -1.0f), 1.0f);
    }
    *(float4*)&outL[t] = make_float4(lv[0], lv[1], lv[2], lv[3]);
    *(float4*)&outR[t] = make_float4(rv[0], rv[1], rv[2], rv[3]);
}

extern "C" void kernel_launch(void* const* d_in, const int* in_sizes, int n_in,
                              void* d_out, int out_size, void* d_ws, size_t ws_size,
                              hipStream_t stream) {
    (void)in_sizes; (void)n_in; (void)out_size; (void)ws_size;
    const float* B_inh   = (const float*)d_in[0];
    const float* f0_off  = (const float*)d_in[1];
    const float* A0      = (const float*)d_in[2];
    const float* tau1    = (const float*)d_in[3];
    const float* tau2    = (const float*)d_in[4];
    const float* a1      = (const float*)d_in[5];
    const float* beat_hz = (const float*)d_in[6];
    const float* beat_dp = (const float*)d_in[7];
    const float* noise   = (const float*)d_in[8];
    const float* f0      = (const float*)d_in[9];
    const float* wfac    = (const float*)d_in[10];
    float* out = (float*)d_out;
    float* ws  = (float*)d_ws;

    kprep<<<dim3(1), dim3(256), 0, stream>>>(B_inh, f0_off, beat_hz, noise, f0, wfac,
                                             A0, tau1, tau2, a1, beat_dp, ws);

    dim3 gh((T_TOT + TBLK - 1) / TBLK, B_BATCH);
    kharm<<<gh, dim3(512), 0, stream>>>(ws, ws + OFF_HARM,
                                        (unsigned int*)ws + OFF_PEAK);

    dim3 gf((N_SAMP + CHUNK - 1) / CHUNK, B_BATCH);
    kfinal<<<gf, dim3(256), 0, stream>>>(ws, out);
}